// Round 8
// baseline (640.539 us; speedup 1.0000x reference)
//
#include <hip/hip_runtime.h>
#include <hip/hip_bf16.h>
#include <hip/hip_cooperative_groups.h>
#include <math.h>

namespace cg = cooperative_groups;

// ---------------- ws layout (float offsets) ----------------
#define WQ0 0
#define BQ0 320
#define WQ1 384
#define BQ1 4480
#define WQ2 4544
#define BQ2 8640
#define WQ3 8704
#define BQ3 12800
#define WQ4 12864
#define BQ4 12928
#define GT0 12932
#define GT1 13444
#define GT2 15492
// Packed bf16 MFMA B-fragments (hi then lo): 24 frags x 64 lanes x 16B, x2.
#define FRAG_OFF 23684
#define NFRAG 24

typedef __bf16 bf16x8 __attribute__((ext_vector_type(8)));
typedef float floatx4 __attribute__((ext_vector_type(4)));
typedef float floatx2 __attribute__((ext_vector_type(2)));
typedef unsigned int uintx4 __attribute__((ext_vector_type(4)));

__device__ inline floatx4 mfma16(bf16x8 a, bf16x8 b, floatx4 c) {
    return __builtin_amdgcn_mfma_f32_16x16x32_bf16(a, b, c, 0, 0, 0);
}
__device__ inline floatx2 splat2(float c) { return (floatx2){c, c}; }
__device__ inline unsigned int fbits(float f) { return __builtin_bit_cast(unsigned int, f); }
__device__ inline float maskhi(float f) {
    return __builtin_bit_cast(float, fbits(f) & 0xffff0000u);
}
__device__ inline unsigned int pack_bf16(float a, float b) {
    unsigned short ua = __builtin_bit_cast(unsigned short, (__bf16)a);
    unsigned short ub = __builtin_bit_cast(unsigned short, (__bf16)b);
    return (unsigned int)ua | ((unsigned int)ub << 16);
}
// pack the top-16 (truncated bf16) of two floats: one v_perm_b32
__device__ inline unsigned int pack_hi2(float e0, float e1) {
    return __builtin_amdgcn_perm(fbits(e1), fbits(e0), 0x07060302u);
}

// Packed-pair gelu: 0.5*(x + |x|*erf_mag(|x|/sqrt2)), AS 7.1.26 erf (1.5e-7).
__device__ inline floatx2 gelu2(floatx2 x) {
    floatx2 ax = __builtin_elementwise_abs(x);
    floatx2 z  = ax * splat2(0.70710678118654752f);
    floatx2 den = __builtin_elementwise_fma(z, splat2(0.3275911f), splat2(1.0f));
    floatx2 t;
    t.x = __builtin_amdgcn_rcpf(den.x);
    t.y = __builtin_amdgcn_rcpf(den.y);
    floatx2 p = __builtin_elementwise_fma(t, splat2(1.061405429f), splat2(-1.453152027f));
    p = __builtin_elementwise_fma(t, p, splat2(1.421413741f));
    p = __builtin_elementwise_fma(t, p, splat2(-0.284496736f));
    p = __builtin_elementwise_fma(t, p, splat2(0.254829592f));
    p = p * t;
    floatx2 ea = (z * z) * splat2(-1.44269504088896f);
    floatx2 e;
    e.x = __builtin_amdgcn_exp2f(ea.x);
    e.y = __builtin_amdgcn_exp2f(ea.y);
    floatx2 er = __builtin_elementwise_fma(-p, e, splat2(1.0f));
    return __builtin_elementwise_fma(ax, er, x) * splat2(0.5f);
}

__device__ inline float tanh_fast(float x) {
    float e = __builtin_amdgcn_exp2f(x * 2.88539008177793f);
    return fmaf(-2.0f, __builtin_amdgcn_rcpf(e + 1.0f), 1.0f);
}

#define LSTR 68

__device__ void block_minmax(float mn, float mx, float* omn, float* omx,
                             float* smn, float* smx) {
    __syncthreads();
    #pragma unroll
    for (int off = 32; off > 0; off >>= 1) {
        mn = fminf(mn, __shfl_down(mn, off));
        mx = fmaxf(mx, __shfl_down(mx, off));
    }
    int wid = threadIdx.x >> 6, lane = threadIdx.x & 63;
    if (lane == 0) { smn[wid] = mn; smx[wid] = mx; }
    __syncthreads();
    if (threadIdx.x == 0) {
        float a = smn[0], b = smx[0];
        for (int i = 1; i < 4; ++i) { a = fminf(a, smn[i]); b = fmaxf(b, smx[i]); }
        smn[0] = a; smx[0] = b;
    }
    __syncthreads();
    *omn = smn[0]; *omx = smx[0];
}

// _qround forward: round((x-mn)/scale)*scale + mn, scale = max(mx-mn,1e-8)/63
__device__ void quantize_tensor(const float* __restrict__ src, int n,
                                float* __restrict__ dst, float* smn, float* smx) {
    float mn = 3.4e38f, mx = -3.4e38f;
    for (int i = threadIdx.x; i < n; i += blockDim.x) {
        float v = src[i];
        mn = fminf(mn, v); mx = fmaxf(mx, v);
    }
    float gmn, gmx;
    block_minmax(mn, mx, &gmn, &gmx, smn, smx);
    float scale = fmaxf(gmx - gmn, 1e-8f) / 63.0f;
    for (int i = threadIdx.x; i < n; i += blockDim.x) {
        float v = src[i];
        dst[i] = rintf((v - gmn) / scale) * scale + gmn;
    }
}

// ONE cooperative kernel:
//   phase 1 (blocks 0..44): prep — quantize weights, grid argmax tables,
//                           MFMA B-fragment pack (self-contained minmax).
//   grid.sync()
//   phase 2 (all blocks): persistent loop over 128-point tiles, r6 body:
//     32 pts/wave, LDS tile [32][68] f32, 16x16x32 bf16 MFMA hi/lo split.
__global__ __launch_bounds__(256, 4) void vinr_fused(
    const float* __restrict__ x,
    const float* __restrict__ cb0, const float* __restrict__ ind0,
    const float* __restrict__ cb1, const float* __restrict__ ind1,
    const float* __restrict__ cb2, const float* __restrict__ ind2,
    const float* __restrict__ w0, const float* __restrict__ b0,
    const float* __restrict__ w1, const float* __restrict__ b1,
    const float* __restrict__ w2, const float* __restrict__ b2,
    const float* __restrict__ w3, const float* __restrict__ b3,
    const float* __restrict__ w4, const float* __restrict__ b4,
    float* __restrict__ ws, float* __restrict__ out, int N, int ntiles)
{
    __shared__ __align__(16) float hlds[4 * 32 * LSTR];
    __shared__ float smn[4], smx[4];

    // ---------------- phase 1: prep ----------------
    if (blockIdx.x < 10) {
        switch (blockIdx.x) {
            case 0: quantize_tensor(w0, 320, ws + WQ0, smn, smx); break;
            case 1: quantize_tensor(b0, 64, ws + BQ0, smn, smx); break;
            case 2: quantize_tensor(w1, 4096, ws + WQ1, smn, smx); break;
            case 3: quantize_tensor(b1, 64, ws + BQ1, smn, smx); break;
            case 4: quantize_tensor(w2, 4096, ws + WQ2, smn, smx); break;
            case 5: quantize_tensor(b2, 64, ws + BQ2, smn, smx); break;
            case 6: quantize_tensor(w3, 4096, ws + WQ3, smn, smx); break;
            case 7: quantize_tensor(b3, 64, ws + BQ3, smn, smx); break;
            case 8: quantize_tensor(w4, 64, ws + WQ4, smn, smx); break;
            case 9: quantize_tensor(b4, 1, ws + BQ4, smn, smx); break;
        }
    } else if (blockIdx.x < 21) {
        int r = (int)(blockIdx.x - 10) * 256 + (int)threadIdx.x;
        const float* ind = nullptr; const float* cb = nullptr; float* dst = nullptr;
        if (r < 128)       { ind = ind0 + r * 64;          cb = cb0; dst = ws + GT0 + r * 4; }
        else if (r < 640)  { int rr = r - 128;  ind = ind1 + rr * 64; cb = cb1; dst = ws + GT1 + rr * 4; }
        else if (r < 2688) { int rr = r - 640;  ind = ind2 + rr * 64; cb = cb2; dst = ws + GT2 + rr * 4; }
        if (dst) {
            float best = -3.4e38f; int bi = 0;
            for (int j = 0; j < 64; ++j) {
                float v = ind[j];
                if (v > best) { best = v; bi = j; }
            }
            #pragma unroll
            for (int d = 0; d < 4; ++d) dst[d] = cb[bi * 4 + d];
        }
    } else if (blockIdx.x < 45) {
        if (threadIdx.x < 64) {                        // one wave per frag
            int fi = (int)blockIdx.x - 21;             // 0..23
            int lane = (int)threadIdx.x;
            int l = fi >> 3, s = (fi >> 2) & 1, nt = fi & 3;
            const float* w = (l == 0) ? w1 : (l == 1) ? w2 : w3;
            float mn = 3.4e38f, mx = -3.4e38f;
            for (int i = lane; i < 4096; i += 64) {
                float v = w[i];
                mn = fminf(mn, v); mx = fmaxf(mx, v);
            }
            #pragma unroll
            for (int off = 32; off > 0; off >>= 1) {
                mn = fminf(mn, __shfl_xor(mn, off));
                mx = fmaxf(mx, __shfl_xor(mx, off));
            }
            float scale = fmaxf(mx - mn, 1e-8f) / 63.0f;
            int q = lane >> 4, m15 = lane & 15;
            int n = nt * 16 + m15;
            bf16x8 hi, lo;
            #pragma unroll
            for (int j = 0; j < 8; ++j) {
                int k = s * 32 + q * 8 + j;
                float v = w[k * 64 + n];
                v = rintf((v - mn) / scale) * scale + mn;
                __bf16 hb = (__bf16)v;
                hi[j] = hb;
                lo[j] = (__bf16)(v - (float)hb);
            }
            bf16x8* base = (bf16x8*)(ws + FRAG_OFF);
            base[fi * 64 + lane] = hi;
            base[NFRAG * 64 + fi * 64 + lane] = lo;
        }
    }
    __threadfence();               // device-scope release of ws writes
    cg::this_grid().sync();

    // ---------------- phase 2: main ----------------
    int wave = threadIdx.x >> 6, lane = threadIdx.x & 63;
    int q = lane >> 4, m15 = lane & 15;
    int p = lane & 31, half = lane >> 5, j0 = half << 5;
    float* slice = hlds + wave * (32 * LSTR);

    const bf16x8* fh = (const bf16x8*)(ws + FRAG_OFF);
    const bf16x8* fl = fh + NFRAG * 64;

    for (int t = (int)blockIdx.x; t < ntiles; t += (int)gridDim.x) {
        int idx = t * 128 + wave * 32 + p;
        int idxc = min(idx, N - 1);
        float2 xr = ((const float2*)x)[idxc];
        float feat  = xr.x;
        float coord = xr.y;

        float g0 = 0.f, g1 = 0.f, g2 = 0.f, g3 = 0.f;
        const int RES[3]  = {128, 512, 2048};
        const int GOFF[3] = {GT0, GT1, GT2};
        #pragma unroll
        for (int gi = 0; gi < 3; ++gi) {
            int res = RES[gi];
            float c = (coord + 1.0f) * 0.5f * (float)(res - 1);
            int left  = min((int)floorf(c), res - 2);
            int right = max((int)ceilf(c), 1);
            float w = c - (float)left;
            const float4* gt = (const float4*)(ws + GOFF[gi]);
            float4 gl = gt[left];
            float4 gr = gt[right];
            float wm = 1.0f - w;
            g0 += wm * gl.x + w * gr.x;
            g1 += wm * gl.y + w * gr.y;
            g2 += wm * gl.z + w * gr.z;
            g3 += wm * gl.w + w * gr.w;
        }

        // layer 0: 5 -> 64; this lane computes features [j0, j0+32) of point p.
        {
            const floatx2* w0v = (const floatx2*)(ws + WQ0);
            const floatx2* b0v = (const floatx2*)(ws + BQ0);
            float* row = slice + p * LSTR + j0;
            int jh = j0 >> 1;
            #pragma unroll
            for (int jj = 0; jj < 16; ++jj) {
                floatx2 a = b0v[jh + jj];
                a = __builtin_elementwise_fma(splat2(g0),   w0v[jh + jj],        a);
                a = __builtin_elementwise_fma(splat2(g1),   w0v[32 + jh + jj],   a);
                a = __builtin_elementwise_fma(splat2(g2),   w0v[64 + jh + jj],   a);
                a = __builtin_elementwise_fma(splat2(g3),   w0v[96 + jh + jj],   a);
                a = __builtin_elementwise_fma(splat2(feat), w0v[128 + jh + jj],  a);
                *(floatx2*)(row + 2 * jj) = gelu2(a);
            }
        }

        const int BQL[3] = {BQ1, BQ2, BQ3};
        #pragma unroll 1
        for (int l = 0; l < 3; ++l) {
            floatx4 acc[2][4];
            #pragma unroll
            for (int mt = 0; mt < 2; ++mt)
                #pragma unroll
                for (int nt = 0; nt < 4; ++nt)
                    acc[mt][nt] = (floatx4){0.f, 0.f, 0.f, 0.f};

            #pragma unroll
            for (int s = 0; s < 2; ++s) {
                bf16x8 Ah[2], Al[2];
                #pragma unroll
                for (int mt = 0; mt < 2; ++mt) {
                    const float* ap = slice + (mt * 16 + m15) * LSTR + s * 32 + q * 8;
                    float4 xa = *(const float4*)ap;
                    float4 xb = *(const float4*)(ap + 4);
                    unsigned int h01 = pack_hi2(xa.x, xa.y);
                    unsigned int h23 = pack_hi2(xa.z, xa.w);
                    unsigned int h45 = pack_hi2(xb.x, xb.y);
                    unsigned int h67 = pack_hi2(xb.z, xb.w);
                    unsigned int l01 = pack_bf16(xa.x - maskhi(xa.x), xa.y - maskhi(xa.y));
                    unsigned int l23 = pack_bf16(xa.z - maskhi(xa.z), xa.w - maskhi(xa.w));
                    unsigned int l45 = pack_bf16(xb.x - maskhi(xb.x), xb.y - maskhi(xb.y));
                    unsigned int l67 = pack_bf16(xb.z - maskhi(xb.z), xb.w - maskhi(xb.w));
                    Ah[mt] = __builtin_bit_cast(bf16x8, (uintx4){h01, h23, h45, h67});
                    Al[mt] = __builtin_bit_cast(bf16x8, (uintx4){l01, l23, l45, l67});
                }
                #pragma unroll
                for (int nt = 0; nt < 4; ++nt) {
                    int fi = (l * 2 + s) * 4 + nt;
                    bf16x8 Bh = fh[fi * 64 + lane];
                    bf16x8 Bl = fl[fi * 64 + lane];
                    #pragma unroll
                    for (int mt = 0; mt < 2; ++mt) {
                        acc[mt][nt] = mfma16(Ah[mt], Bh, acc[mt][nt]);
                        acc[mt][nt] = mfma16(Ah[mt], Bl, acc[mt][nt]);
                        acc[mt][nt] = mfma16(Al[mt], Bh, acc[mt][nt]);
                    }
                }
            }
            // epilogue: +bias, gelu, store back (C: row=q*4+r, col=m15).
            const float* bq = ws + BQL[l];
            #pragma unroll
            for (int nt = 0; nt < 4; ++nt) {
                float bias = bq[nt * 16 + m15];
                #pragma unroll
                for (int mt = 0; mt < 2; ++mt) {
                    floatx4 av = acc[mt][nt];
                    floatx2 v01 = gelu2((floatx2){av[0] + bias, av[1] + bias});
                    floatx2 v23 = gelu2((floatx2){av[2] + bias, av[3] + bias});
                    float* wbase = slice + (mt * 16 + q * 4) * LSTR + nt * 16 + m15;
                    wbase[0]        = v01.x;
                    wbase[LSTR]     = v01.y;
                    wbase[2 * LSTR] = v23.x;
                    wbase[3 * LSTR] = v23.y;
                }
            }
        }

        // layer 4: half-dot over features [j0, j0+32), combine via shfl.
        {
            const floatx2* w4v = (const floatx2*)(ws + WQ4);
            float acc4 = (half == 0) ? ws[BQ4] : 0.0f;
            const float* row = slice + p * LSTR + j0;
            floatx2 a2 = splat2(0.0f);
            #pragma unroll
            for (int c = 0; c < 8; ++c) {
                float4 v = *(const float4*)(row + 4 * c);
                a2 = __builtin_elementwise_fma((floatx2){v.x, v.y}, w4v[(j0 >> 1) + 2 * c],     a2);
                a2 = __builtin_elementwise_fma((floatx2){v.z, v.w}, w4v[(j0 >> 1) + 2 * c + 1], a2);
            }
            acc4 += a2.x + a2.y;
            acc4 += __shfl_xor(acc4, 32);
            if (half == 0 && idx < N) out[idx] = tanh_fast(acc4);
        }
    }
}

extern "C" void kernel_launch(void* const* d_in, const int* in_sizes, int n_in,
                              void* d_out, int out_size, void* d_ws, size_t ws_size,
                              hipStream_t stream) {
    const float* x    = (const float*)d_in[0];
    const float* cb0  = (const float*)d_in[1];
    const float* ind0 = (const float*)d_in[2];
    const float* cb1  = (const float*)d_in[3];
    const float* ind1 = (const float*)d_in[4];
    const float* cb2  = (const float*)d_in[5];
    const float* ind2 = (const float*)d_in[6];
    const float* w0 = (const float*)d_in[7],  * b0 = (const float*)d_in[8];
    const float* w1 = (const float*)d_in[9],  * b1 = (const float*)d_in[10];
    const float* w2 = (const float*)d_in[11], * b2 = (const float*)d_in[12];
    const float* w3 = (const float*)d_in[13], * b3 = (const float*)d_in[14];
    const float* w4 = (const float*)d_in[15], * b4 = (const float*)d_in[16];
    float* ws  = (float*)d_ws;
    float* out = (float*)d_out;

    int N = in_sizes[0] / 2;           // 1<<20
    int ntiles = (N + 127) / 128;      // 8192

    // Co-resident grid size for cooperative launch (host-side, capture-safe).
    int blocks_per_cu = 0;
    hipOccupancyMaxActiveBlocksPerMultiprocessor(&blocks_per_cu,
        (const void*)vinr_fused, 256, 0);
    if (blocks_per_cu < 1) blocks_per_cu = 1;
    int num_cu = 0;
    hipDeviceGetAttribute(&num_cu, hipDeviceAttributeMultiprocessorCount, 0);
    if (num_cu < 1) num_cu = 256;
    int grid = blocks_per_cu * num_cu;
    if (grid > ntiles) grid = ntiles;
    if (grid < 45) grid = 45;

    void* args[] = {
        (void*)&x, (void*)&cb0, (void*)&ind0, (void*)&cb1, (void*)&ind1,
        (void*)&cb2, (void*)&ind2, (void*)&w0, (void*)&b0, (void*)&w1,
        (void*)&b1, (void*)&w2, (void*)&b2, (void*)&w3, (void*)&b3,
        (void*)&w4, (void*)&b4, (void*)&ws, (void*)&out, (void*)&N,
        (void*)&ntiles
    };
    hipLaunchCooperativeKernel((const void*)vinr_fused, dim3(grid), dim3(256),
                               args, 0, stream);
}

// Round 9
// 267.592 us; speedup vs baseline: 2.3937x; 2.3937x over previous
//
#include <hip/hip_runtime.h>
#include <hip/hip_bf16.h>
#include <math.h>

// ---------------- ws layout (float offsets) ----------------
#define WQ0 0
#define BQ0 320
#define WQ1 384
#define BQ1 4480
#define WQ2 4544
#define BQ2 8640
#define WQ3 8704
#define BQ3 12800
#define WQ4 12864
#define BQ4 12928
#define GT0 12932
#define GT1 13444
#define GT2 15492
// Packed bf16 MFMA B-fragments (hi block then lo block):
// fi 0..23 = layers 1..3 ((l*2+s)*4+nt), fi 24..27 = layer 0 (nt, s=0, K rows 5..31 zero).
// 28 frags x 64 lanes x 16B x2 = 57344 B at float offset 23684.
#define FRAG_OFF 23684
#define NFRAG 28

typedef __bf16 bf16x8 __attribute__((ext_vector_type(8)));
typedef float floatx4 __attribute__((ext_vector_type(4)));
typedef float floatx2 __attribute__((ext_vector_type(2)));
typedef unsigned int uintx4 __attribute__((ext_vector_type(4)));

__device__ inline floatx4 mfma16(bf16x8 a, bf16x8 b, floatx4 c) {
    return __builtin_amdgcn_mfma_f32_16x16x32_bf16(a, b, c, 0, 0, 0);
}
__device__ inline floatx2 splat2(float c) { return (floatx2){c, c}; }
__device__ inline unsigned int fbits(float f) { return __builtin_bit_cast(unsigned int, f); }
__device__ inline float maskhi(float f) {
    return __builtin_bit_cast(float, fbits(f) & 0xffff0000u);
}
__device__ inline unsigned int pack_bf16(float a, float b) {
    unsigned short ua = __builtin_bit_cast(unsigned short, (__bf16)a);
    unsigned short ub = __builtin_bit_cast(unsigned short, (__bf16)b);
    return (unsigned int)ua | ((unsigned int)ub << 16);
}
// pack the top-16 (truncated bf16) of two floats: one v_perm_b32
__device__ inline unsigned int pack_hi2(float e0, float e1) {
    return __builtin_amdgcn_perm(fbits(e1), fbits(e0), 0x07060302u);
}

// Packed-pair gelu: 0.5*(x + |x|*erf_mag(|x|/sqrt2)), AS 7.1.26 erf (1.5e-7).
__device__ inline floatx2 gelu2(floatx2 x) {
    floatx2 ax = __builtin_elementwise_abs(x);
    floatx2 z  = ax * splat2(0.70710678118654752f);
    floatx2 den = __builtin_elementwise_fma(z, splat2(0.3275911f), splat2(1.0f));
    floatx2 t;
    t.x = __builtin_amdgcn_rcpf(den.x);
    t.y = __builtin_amdgcn_rcpf(den.y);
    floatx2 p = __builtin_elementwise_fma(t, splat2(1.061405429f), splat2(-1.453152027f));
    p = __builtin_elementwise_fma(t, p, splat2(1.421413741f));
    p = __builtin_elementwise_fma(t, p, splat2(-0.284496736f));
    p = __builtin_elementwise_fma(t, p, splat2(0.254829592f));
    p = p * t;
    floatx2 ea = (z * z) * splat2(-1.44269504088896f);
    floatx2 e;
    e.x = __builtin_amdgcn_exp2f(ea.x);
    e.y = __builtin_amdgcn_exp2f(ea.y);
    floatx2 er = __builtin_elementwise_fma(-p, e, splat2(1.0f));
    return __builtin_elementwise_fma(ax, er, x) * splat2(0.5f);
}

__device__ inline float tanh_fast(float x) {
    float e = __builtin_amdgcn_exp2f(x * 2.88539008177793f);
    return fmaf(-2.0f, __builtin_amdgcn_rcpf(e + 1.0f), 1.0f);
}

__device__ void block_minmax(float mn, float mx, float* omn, float* omx,
                             float* smn, float* smx) {
    __syncthreads();
    #pragma unroll
    for (int off = 32; off > 0; off >>= 1) {
        mn = fminf(mn, __shfl_down(mn, off));
        mx = fmaxf(mx, __shfl_down(mx, off));
    }
    int wid = threadIdx.x >> 6, lane = threadIdx.x & 63;
    if (lane == 0) { smn[wid] = mn; smx[wid] = mx; }
    __syncthreads();
    if (threadIdx.x == 0) {
        float a = smn[0], b = smx[0];
        for (int i = 1; i < 4; ++i) { a = fminf(a, smn[i]); b = fmaxf(b, smx[i]); }
        smn[0] = a; smx[0] = b;
    }
    __syncthreads();
    *omn = smn[0]; *omx = smx[0];
}

// _qround forward: round((x-mn)/scale)*scale + mn, scale = max(mx-mn,1e-8)/63
__device__ void quantize_tensor(const float* __restrict__ src, int n,
                                float* __restrict__ dst, float* smn, float* smx) {
    float mn = 3.4e38f, mx = -3.4e38f;
    for (int i = threadIdx.x; i < n; i += blockDim.x) {
        float v = src[i];
        mn = fminf(mn, v); mx = fmaxf(mx, v);
    }
    float gmn, gmx;
    block_minmax(mn, mx, &gmn, &gmx, smn, smx);
    float scale = fmaxf(gmx - gmn, 1e-8f) / 63.0f;
    for (int i = threadIdx.x; i < n; i += blockDim.x) {
        float v = src[i];
        dst[i] = rintf((v - gmn) / scale) * scale + gmn;
    }
}

// ONE prep launch (46 blocks):
//   0..9   : quantize weight/bias tensors into ws
//   10..20 : grid argmax tables (one thread per grid row)
//   21..44 : B-fragments, layers 1..3 (self-contained minmax; min/max are
//            order-independent so quantization is bit-identical)
//   45     : B-fragments, layer 0 (4 waves, one per n-tile; K rows 5..31 zero)
__global__ void vinr_prep(
    const float* __restrict__ cb0, const float* __restrict__ ind0,
    const float* __restrict__ cb1, const float* __restrict__ ind1,
    const float* __restrict__ cb2, const float* __restrict__ ind2,
    const float* __restrict__ w0, const float* __restrict__ b0,
    const float* __restrict__ w1, const float* __restrict__ b1,
    const float* __restrict__ w2, const float* __restrict__ b2,
    const float* __restrict__ w3, const float* __restrict__ b3,
    const float* __restrict__ w4, const float* __restrict__ b4,
    float* __restrict__ ws)
{
    __shared__ float smn[4], smx[4];
    if (blockIdx.x < 10) {
        switch (blockIdx.x) {
            case 0: quantize_tensor(w0, 320, ws + WQ0, smn, smx); break;
            case 1: quantize_tensor(b0, 64, ws + BQ0, smn, smx); break;
            case 2: quantize_tensor(w1, 4096, ws + WQ1, smn, smx); break;
            case 3: quantize_tensor(b1, 64, ws + BQ1, smn, smx); break;
            case 4: quantize_tensor(w2, 4096, ws + WQ2, smn, smx); break;
            case 5: quantize_tensor(b2, 64, ws + BQ2, smn, smx); break;
            case 6: quantize_tensor(w3, 4096, ws + WQ3, smn, smx); break;
            case 7: quantize_tensor(b3, 64, ws + BQ3, smn, smx); break;
            case 8: quantize_tensor(w4, 64, ws + WQ4, smn, smx); break;
            case 9: quantize_tensor(b4, 1, ws + BQ4, smn, smx); break;
        }
    } else if (blockIdx.x < 21) {
        int r = (int)(blockIdx.x - 10) * 256 + (int)threadIdx.x;
        const float* ind = nullptr; const float* cb = nullptr; float* dst = nullptr;
        if (r < 128)       { ind = ind0 + r * 64;          cb = cb0; dst = ws + GT0 + r * 4; }
        else if (r < 640)  { int rr = r - 128;  ind = ind1 + rr * 64; cb = cb1; dst = ws + GT1 + rr * 4; }
        else if (r < 2688) { int rr = r - 640;  ind = ind2 + rr * 64; cb = cb2; dst = ws + GT2 + rr * 4; }
        if (dst) {
            float best = -3.4e38f; int bi = 0;
            for (int j = 0; j < 64; ++j) {
                float v = ind[j];
                if (v > best) { best = v; bi = j; }
            }
            #pragma unroll
            for (int d = 0; d < 4; ++d) dst[d] = cb[bi * 4 + d];
        }
    } else if (blockIdx.x < 45) {
        if (threadIdx.x < 64) {                        // one wave per frag
            int fi = (int)blockIdx.x - 21;             // 0..23
            int lane = (int)threadIdx.x;
            int l = fi >> 3, s = (fi >> 2) & 1, nt = fi & 3;
            const float* w = (l == 0) ? w1 : (l == 1) ? w2 : w3;
            float mn = 3.4e38f, mx = -3.4e38f;
            for (int i = lane; i < 4096; i += 64) {
                float v = w[i];
                mn = fminf(mn, v); mx = fmaxf(mx, v);
            }
            #pragma unroll
            for (int off = 32; off > 0; off >>= 1) {
                mn = fminf(mn, __shfl_xor(mn, off));
                mx = fmaxf(mx, __shfl_xor(mx, off));
            }
            float scale = fmaxf(mx - mn, 1e-8f) / 63.0f;
            int q = lane >> 4, m15 = lane & 15;
            int n = nt * 16 + m15;
            bf16x8 hi, lo;
            #pragma unroll
            for (int j = 0; j < 8; ++j) {
                int k = s * 32 + q * 8 + j;
                float v = w[k * 64 + n];
                v = rintf((v - mn) / scale) * scale + mn;
                __bf16 hb = (__bf16)v;
                hi[j] = hb;
                lo[j] = (__bf16)(v - (float)hb);
            }
            bf16x8* base = (bf16x8*)(ws + FRAG_OFF);
            base[fi * 64 + lane] = hi;
            base[NFRAG * 64 + fi * 64 + lane] = lo;
        }
    } else {
        // layer-0 frags: wave wv -> n-tile wv; W0 is [5][64], K padded to 32 with zeros.
        int wv = (int)threadIdx.x >> 6;
        int lane = (int)threadIdx.x & 63;
        if (wv < 4) {
            float mn = 3.4e38f, mx = -3.4e38f;
            for (int i = lane; i < 320; i += 64) {
                float v = w0[i];
                mn = fminf(mn, v); mx = fmaxf(mx, v);
            }
            #pragma unroll
            for (int off = 32; off > 0; off >>= 1) {
                mn = fminf(mn, __shfl_xor(mn, off));
                mx = fmaxf(mx, __shfl_xor(mx, off));
            }
            float scale = fmaxf(mx - mn, 1e-8f) / 63.0f;
            int q = lane >> 4, m15 = lane & 15;
            int n = wv * 16 + m15;
            bf16x8 hi, lo;
            #pragma unroll
            for (int j = 0; j < 8; ++j) {
                int k = q * 8 + j;
                float v = 0.0f;
                if (k < 5) {
                    float vv = w0[k * 64 + n];
                    v = rintf((vv - mn) / scale) * scale + mn;
                }
                __bf16 hb = (__bf16)v;
                hi[j] = hb;
                lo[j] = (__bf16)(v - (float)hb);
            }
            bf16x8* base = (bf16x8*)(ws + FRAG_OFF);
            base[(24 + wv) * 64 + lane] = hi;
            base[NFRAG * 64 + (24 + wv) * 64 + lane] = lo;
        }
    }
}

// 32 points per wave; activations in wave-private LDS tile [32][68] f32.
// Layers 0-3 via 16x16x32 bf16 MFMA with hi/lo split (3 MFMA per tile-pair);
// layer 0 uses K=32 padded frags. Layer 4 per-lane dot (features split across
// lane halves). No __syncthreads in main body: slices are wave-private,
// per-wave DS ops are in-order.
#define LSTR 68

__global__ __launch_bounds__(256, 4) void vinr_main(
    const float* __restrict__ x, const float* __restrict__ ws,
    float* __restrict__ out, int N)
{
    __shared__ __align__(16) float hlds[4 * 32 * LSTR];
    int wave = threadIdx.x >> 6, lane = threadIdx.x & 63;
    int q = lane >> 4, m15 = lane & 15;
    int p = lane & 31, half = lane >> 5, j0 = half << 5;
    float* slice = hlds + wave * (32 * LSTR);

    int idx = (int)blockIdx.x * 128 + wave * 32 + p;
    int idxc = min(idx, N - 1);
    float2 xr = ((const float2*)x)[idxc];
    float feat  = xr.x;
    float coord = xr.y;

    float g0 = 0.f, g1 = 0.f, g2 = 0.f, g3 = 0.f;
    const int RES[3]  = {128, 512, 2048};
    const int GOFF[3] = {GT0, GT1, GT2};
    #pragma unroll
    for (int gi = 0; gi < 3; ++gi) {
        int res = RES[gi];
        float c = (coord + 1.0f) * 0.5f * (float)(res - 1);
        int left  = min((int)floorf(c), res - 2);
        int right = max((int)ceilf(c), 1);
        float w = c - (float)left;
        const float4* gt = (const float4*)(ws + GOFF[gi]);
        float4 gl = gt[left];
        float4 gr = gt[right];
        float wm = 1.0f - w;
        g0 += wm * gl.x + w * gr.x;
        g1 += wm * gl.y + w * gr.y;
        g2 += wm * gl.z + w * gr.z;
        g3 += wm * gl.w + w * gr.w;
    }

    const bf16x8* fh = (const bf16x8*)(ws + FRAG_OFF);
    const bf16x8* fl = fh + NFRAG * 64;
    bf16x8 zfrag = __builtin_bit_cast(bf16x8, (uintx4){0u, 0u, 0u, 0u});

    // stage layer-0 A inputs: row p = [g0,g1,g2,g3,feat,0,0,0] (half 0 only)
    if (half == 0) {
        float* row = slice + p * LSTR;
        *(float4*)row = make_float4(g0, g1, g2, g3);
        *(float4*)(row + 4) = make_float4(feat, 0.0f, 0.0f, 0.0f);
    }

    // ---- layer 0 (5 -> 64) via MFMA, K=32 padded; rows k>=8 are zero so
    //      only q==0 lanes carry real A data (others contribute zero frags).
    {
        bf16x8 Bh[4], Bl[4];
        #pragma unroll
        for (int nt = 0; nt < 4; ++nt) {
            Bh[nt] = fh[(24 + nt) * 64 + lane];
            Bl[nt] = fl[(24 + nt) * 64 + lane];
        }
        bf16x8 Ah[2], Al[2];
        #pragma unroll
        for (int mt = 0; mt < 2; ++mt) {
            Ah[mt] = zfrag; Al[mt] = zfrag;
            if (q == 0) {
                const float* ap = slice + (mt * 16 + m15) * LSTR;
                float4 xa = *(const float4*)ap;
                float4 xb = *(const float4*)(ap + 4);
                unsigned int h01 = pack_hi2(xa.x, xa.y);
                unsigned int h23 = pack_hi2(xa.z, xa.w);
                unsigned int h45 = pack_hi2(xb.x, xb.y);
                unsigned int h67 = pack_hi2(xb.z, xb.w);
                unsigned int l01 = pack_bf16(xa.x - maskhi(xa.x), xa.y - maskhi(xa.y));
                unsigned int l23 = pack_bf16(xa.z - maskhi(xa.z), xa.w - maskhi(xa.w));
                unsigned int l45 = pack_bf16(xb.x - maskhi(xb.x), xb.y - maskhi(xb.y));
                unsigned int l67 = pack_bf16(xb.z - maskhi(xb.z), xb.w - maskhi(xb.w));
                Ah[mt] = __builtin_bit_cast(bf16x8, (uintx4){h01, h23, h45, h67});
                Al[mt] = __builtin_bit_cast(bf16x8, (uintx4){l01, l23, l45, l67});
            }
        }
        floatx4 acc[2][4];
        #pragma unroll
        for (int mt = 0; mt < 2; ++mt)
            #pragma unroll
            for (int nt = 0; nt < 4; ++nt)
                acc[mt][nt] = (floatx4){0.f, 0.f, 0.f, 0.f};
        #pragma unroll
        for (int nt = 0; nt < 4; ++nt)
            #pragma unroll
            for (int mt = 0; mt < 2; ++mt) {
                acc[mt][nt] = mfma16(Ah[mt], Bh[nt], acc[mt][nt]);
                acc[mt][nt] = mfma16(Ah[mt], Bl[nt], acc[mt][nt]);
                acc[mt][nt] = mfma16(Al[mt], Bh[nt], acc[mt][nt]);
            }
        const float* bq = ws + BQ0;
        #pragma unroll
        for (int nt = 0; nt < 4; ++nt) {
            float bias = bq[nt * 16 + m15];
            #pragma unroll
            for (int mt = 0; mt < 2; ++mt) {
                floatx4 av = acc[mt][nt];
                floatx2 v01 = gelu2((floatx2){av[0] + bias, av[1] + bias});
                floatx2 v23 = gelu2((floatx2){av[2] + bias, av[3] + bias});
                float* wbase = slice + (mt * 16 + q * 4) * LSTR + nt * 16 + m15;
                wbase[0]        = v01.x;
                wbase[LSTR]     = v01.y;
                wbase[2 * LSTR] = v23.x;
                wbase[3 * LSTR] = v23.y;
            }
        }
    }

    // ---- layers 1..3
    const int BQL[3] = {BQ1, BQ2, BQ3};
    #pragma unroll 1
    for (int l = 0; l < 3; ++l) {
        floatx4 acc[2][4];
        #pragma unroll
        for (int mt = 0; mt < 2; ++mt)
            #pragma unroll
            for (int nt = 0; nt < 4; ++nt)
                acc[mt][nt] = (floatx4){0.f, 0.f, 0.f, 0.f};

        #pragma unroll
        for (int s = 0; s < 2; ++s) {
            // hoist all B-frag loads so L2 latency overlaps the A-pack VALU
            bf16x8 Bh[4], Bl[4];
            #pragma unroll
            for (int nt = 0; nt < 4; ++nt) {
                int fi = (l * 2 + s) * 4 + nt;
                Bh[nt] = fh[fi * 64 + lane];
                Bl[nt] = fl[fi * 64 + lane];
            }
            bf16x8 Ah[2], Al[2];
            #pragma unroll
            for (int mt = 0; mt < 2; ++mt) {
                const float* ap = slice + (mt * 16 + m15) * LSTR + s * 32 + q * 8;
                float4 xa = *(const float4*)ap;
                float4 xb = *(const float4*)(ap + 4);
                unsigned int h01 = pack_hi2(xa.x, xa.y);
                unsigned int h23 = pack_hi2(xa.z, xa.w);
                unsigned int h45 = pack_hi2(xb.x, xb.y);
                unsigned int h67 = pack_hi2(xb.z, xb.w);
                unsigned int l01 = pack_bf16(xa.x - maskhi(xa.x), xa.y - maskhi(xa.y));
                unsigned int l23 = pack_bf16(xa.z - maskhi(xa.z), xa.w - maskhi(xa.w));
                unsigned int l45 = pack_bf16(xb.x - maskhi(xb.x), xb.y - maskhi(xb.y));
                unsigned int l67 = pack_bf16(xb.z - maskhi(xb.z), xb.w - maskhi(xb.w));
                Ah[mt] = __builtin_bit_cast(bf16x8, (uintx4){h01, h23, h45, h67});
                Al[mt] = __builtin_bit_cast(bf16x8, (uintx4){l01, l23, l45, l67});
            }
            #pragma unroll
            for (int nt = 0; nt < 4; ++nt) {
                #pragma unroll
                for (int mt = 0; mt < 2; ++mt) {
                    acc[mt][nt] = mfma16(Ah[mt], Bh[nt], acc[mt][nt]);
                    acc[mt][nt] = mfma16(Ah[mt], Bl[nt], acc[mt][nt]);
                    acc[mt][nt] = mfma16(Al[mt], Bh[nt], acc[mt][nt]);
                }
            }
        }
        // epilogue: +bias, gelu, store back (C: row=q*4+r, col=m15).
        const float* bq = ws + BQL[l];
        #pragma unroll
        for (int nt = 0; nt < 4; ++nt) {
            float bias = bq[nt * 16 + m15];
            #pragma unroll
            for (int mt = 0; mt < 2; ++mt) {
                floatx4 av = acc[mt][nt];
                floatx2 v01 = gelu2((floatx2){av[0] + bias, av[1] + bias});
                floatx2 v23 = gelu2((floatx2){av[2] + bias, av[3] + bias});
                float* wbase = slice + (mt * 16 + q * 4) * LSTR + nt * 16 + m15;
                wbase[0]        = v01.x;
                wbase[LSTR]     = v01.y;
                wbase[2 * LSTR] = v23.x;
                wbase[3 * LSTR] = v23.y;
            }
        }
    }

    // layer 4: half-dot over features [j0, j0+32), combine via shfl.
    {
        const floatx2* w4v = (const floatx2*)(ws + WQ4);
        float acc4 = (half == 0) ? ws[BQ4] : 0.0f;
        const float* row = slice + p * LSTR + j0;
        floatx2 a2 = splat2(0.0f);
        #pragma unroll
        for (int c = 0; c < 8; ++c) {
            float4 v = *(const float4*)(row + 4 * c);
            a2 = __builtin_elementwise_fma((floatx2){v.x, v.y}, w4v[(j0 >> 1) + 2 * c],     a2);
            a2 = __builtin_elementwise_fma((floatx2){v.z, v.w}, w4v[(j0 >> 1) + 2 * c + 1], a2);
        }
        acc4 += a2.x + a2.y;
        acc4 += __shfl_xor(acc4, 32);
        if (half == 0 && idx < N) out[idx] = tanh_fast(acc4);
    }
}

extern "C" void kernel_launch(void* const* d_in, const int* in_sizes, int n_in,
                              void* d_out, int out_size, void* d_ws, size_t ws_size,
                              hipStream_t stream) {
    const float* x    = (const float*)d_in[0];
    const float* cb0  = (const float*)d_in[1];
    const float* ind0 = (const float*)d_in[2];
    const float* cb1  = (const float*)d_in[3];
    const float* ind1 = (const float*)d_in[4];
    const float* cb2  = (const float*)d_in[5];
    const float* ind2 = (const float*)d_in[6];
    const float* w0 = (const float*)d_in[7],  * b0 = (const float*)d_in[8];
    const float* w1 = (const float*)d_in[9],  * b1 = (const float*)d_in[10];
    const float* w2 = (const float*)d_in[11], * b2 = (const float*)d_in[12];
    const float* w3 = (const float*)d_in[13], * b3 = (const float*)d_in[14];
    const float* w4 = (const float*)d_in[15], * b4 = (const float*)d_in[16];
    float* ws  = (float*)d_ws;
    float* out = (float*)d_out;

    int N = in_sizes[0] / 2;  // 1<<20

    vinr_prep<<<46, 256, 0, stream>>>(cb0, ind0, cb1, ind1, cb2, ind2,
                                      w0, b0, w1, b1, w2, b2, w3, b3, w4, b4, ws);
    int blocks = (N + 127) / 128;
    vinr_main<<<blocks, 256, 0, stream>>>(x, ws, out, N);
}